// Round 1
// baseline (116.603 us; speedup 1.0000x reference)
//
#include <hip/hip_runtime.h>
#include <math.h>

#define NUM_TOKENS 16384
#define HIDDEN 2048
#define NUM_EXPERTS 64
#define TOPK 2

// tile config
#define TM 64          // tokens per block
#define KH 64          // h-chunk staged per iteration
#define XS_STR 68      // padded stride for x tile / logits (floats, 16B-aligned)

// out layout (fp32 flat): [0,32768) weights [t][k]; [32768,65536) indices as float; [65536] aux_loss
#define IDX_OFF 32768
#define AUX_OFF 65536

__global__ __launch_bounds__(256) void router_kernel(
    const float* __restrict__ x, const float* __restrict__ Wg,
    float* __restrict__ out, float* __restrict__ ws)
{
    __shared__ float sA[TM * XS_STR];        // x tile, later logits
    __shared__ float sB[KH * NUM_EXPERTS];   // W tile, later reduce scratch

    const int tid = threadIdx.x;
    const int bid = blockIdx.x;
    const int tx = tid & 15;      // expert group (4 experts each)
    const int ty = tid >> 4;      // token group (4 tokens each)
    const int tokBase = bid * TM;

    float C[4][4] = {{0.f,0.f,0.f,0.f},{0.f,0.f,0.f,0.f},{0.f,0.f,0.f,0.f},{0.f,0.f,0.f,0.f}};

    for (int hb = 0; hb < HIDDEN; hb += KH) {
        // ---- stage x tile: 64 tokens x 64 h ----
        #pragma unroll
        for (int p = 0; p < 4; ++p) {
            int li = p * 256 + tid;          // 0..1023
            int t  = li >> 4;
            int hq = li & 15;
            float4 v = *reinterpret_cast<const float4*>(
                &x[(size_t)(tokBase + t) * HIDDEN + hb + hq * 4]);
            *reinterpret_cast<float4*>(&sA[t * XS_STR + hq * 4]) = v;
        }
        // ---- stage W chunk: rows hb..hb+63, contiguous 16KB ----
        #pragma unroll
        for (int p = 0; p < 4; ++p) {
            int li = p * 256 + tid;
            float4 v = *reinterpret_cast<const float4*>(
                &Wg[(size_t)hb * NUM_EXPERTS + li * 4]);
            *reinterpret_cast<float4*>(&sB[li * 4]) = v;
        }
        __syncthreads();

        // ---- compute: rank-4 updates, C[4 tokens][4 experts] ----
        #pragma unroll
        for (int k4 = 0; k4 < KH / 4; ++k4) {
            float xa[4][4];  // [token i][kk]
            float wa[4][4];  // [kk][expert jj]
            #pragma unroll
            for (int i = 0; i < 4; ++i) {
                float4 v = *reinterpret_cast<const float4*>(
                    &sA[(ty * 4 + i) * XS_STR + k4 * 4]);
                xa[i][0] = v.x; xa[i][1] = v.y; xa[i][2] = v.z; xa[i][3] = v.w;
            }
            #pragma unroll
            for (int kk = 0; kk < 4; ++kk) {
                float4 v = *reinterpret_cast<const float4*>(
                    &sB[(k4 * 4 + kk) * NUM_EXPERTS + tx * 4]);
                wa[kk][0] = v.x; wa[kk][1] = v.y; wa[kk][2] = v.z; wa[kk][3] = v.w;
            }
            #pragma unroll
            for (int i = 0; i < 4; ++i)
                #pragma unroll
                for (int kk = 0; kk < 4; ++kk)
                    #pragma unroll
                    for (int jj = 0; jj < 4; ++jj)
                        C[i][jj] = fmaf(xa[i][kk], wa[kk][jj], C[i][jj]);
        }
        __syncthreads();
    }

    // ---- write logits to LDS (reuse sA) ----
    #pragma unroll
    for (int i = 0; i < 4; ++i) {
        float4 v; v.x = C[i][0]; v.y = C[i][1]; v.z = C[i][2]; v.w = C[i][3];
        *reinterpret_cast<float4*>(&sA[(ty * 4 + i) * XS_STR + tx * 4]) = v;
    }
    __syncthreads();

    // ---- wave-per-token softmax + top-2 ----
    const int wave = tid >> 6;   // 0..3
    const int lane = tid & 63;   // expert id for this lane
    float accP = 0.f;            // sum of probs[lane] over this wave's tokens
    float accC = 0.f;            // count of top1==lane

    for (int tt = 0; tt < TM / 4; ++tt) {
        int t = wave * (TM / 4) + tt;
        float l = sA[t * XS_STR + lane];

        // max
        float m = l;
        #pragma unroll
        for (int off = 32; off >= 1; off >>= 1) m = fmaxf(m, __shfl_xor(m, off));
        float p = expf(l - m);
        // denom
        float Z = p;
        #pragma unroll
        for (int off = 32; off >= 1; off >>= 1) Z += __shfl_xor(Z, off);
        float prob = p / Z;

        // top1 (argmax, tie -> lowest index, matches lax.top_k)
        float v1 = prob; int i1 = lane;
        #pragma unroll
        for (int off = 32; off >= 1; off >>= 1) {
            float ov = __shfl_xor(v1, off);
            int   oi = __shfl_xor(i1, off);
            if (ov > v1 || (ov == v1 && oi < i1)) { v1 = ov; i1 = oi; }
        }
        // top2
        float v2 = (lane == i1) ? -1.f : prob; int i2 = lane;
        #pragma unroll
        for (int off = 32; off >= 1; off >>= 1) {
            float ov = __shfl_xor(v2, off);
            int   oi = __shfl_xor(i2, off);
            if (ov > v2 || (ov == v2 && oi < i2)) { v2 = ov; i2 = oi; }
        }

        accP += prob;
        if (lane == i1) accC += 1.f;

        if (lane == 0) {
            float s = v1 + v2 + 1e-9f;
            size_t o = (size_t)(tokBase + t) * 2;
            out[o]               = v1 / s;
            out[o + 1]           = v2 / s;
            out[IDX_OFF + o]     = (float)i1;
            out[IDX_OFF + o + 1] = (float)i2;
        }
    }

    // ---- per-block partials -> ws (deterministic, no atomics) ----
    sB[wave * 64 + lane]       = accP;
    sB[256 + wave * 64 + lane] = accC;
    __syncthreads();
    if (tid < 64) {
        float sp = sB[tid] + sB[64 + tid] + sB[128 + tid] + sB[192 + tid];
        float sc = sB[256 + tid] + sB[320 + tid] + sB[384 + tid] + sB[448 + tid];
        ws[(size_t)bid * 128 + tid]      = sp;
        ws[(size_t)bid * 128 + 64 + tid] = sc;
    }
}

__global__ __launch_bounds__(64) void finalize_kernel(
    const float* __restrict__ ws, float* __restrict__ out)
{
    int e = threadIdx.x;  // 0..63
    float sp = 0.f, sc = 0.f;
    for (int b = 0; b < NUM_TOKENS / TM; ++b) {
        sp += ws[(size_t)b * 128 + e];
        sc += ws[(size_t)b * 128 + 64 + e];
    }
    float val = (sc * (1.0f / NUM_TOKENS)) * (sp * (1.0f / NUM_TOKENS));
    #pragma unroll
    for (int off = 32; off >= 1; off >>= 1) val += __shfl_xor(val, off);
    if (e == 0) out[AUX_OFF] = (float)NUM_EXPERTS * val;
}

extern "C" void kernel_launch(void* const* d_in, const int* in_sizes, int n_in,
                              void* d_out, int out_size, void* d_ws, size_t ws_size,
                              hipStream_t stream) {
    const float* x  = (const float*)d_in[0];
    const float* Wg = (const float*)d_in[1];
    float* out = (float*)d_out;
    float* ws  = (float*)d_ws;

    router_kernel<<<NUM_TOKENS / TM, 256, 0, stream>>>(x, Wg, out, ws);
    finalize_kernel<<<1, 64, 0, stream>>>(ws, out);
}